// Round 2
// baseline (927.635 us; speedup 1.0000x reference)
//
#include <hip/hip_runtime.h>
#include <stdint.h>

#define THRESH_ 0.3f
constexpr int B_ = 256, WIN_ = 100, NIN_ = 700, NINP_ = 704, H_ = 512;
constexpr int NOUT_ = 20, NOUTP_ = 32, ND_ = 10, KBIG_ = 5120, M_ = 25600;
constexpr int PLANES_ = 140;  // 40 zero-history + 100

typedef unsigned short u16;
typedef unsigned short u16x8 __attribute__((ext_vector_type(8)));
typedef float f32x4 __attribute__((ext_vector_type(4)));

// ---- fp16 RNE split (for GEMM0) ----
__device__ __forceinline__ u16 f2h(float f) {
  _Float16 h = (_Float16)f;           // RNE
  union { _Float16 h; u16 u; } v; v.h = h;
  return v.u;
}
__device__ __forceinline__ float h2f(u16 u) {
  union { u16 u; _Float16 h; } v; v.u = u;
  return (float)v.h;
}
// ---- truncating bf16 3-way split (bit-exact: v == h+m+l) ----
__device__ __forceinline__ float bfu2f(u16 h) {
  union { unsigned u; float f; } v; v.u = ((unsigned)h) << 16;
  return v.f;
}
__device__ __forceinline__ void split3_bf(float v, u16& a, u16& b, u16& c) {
  union { float f; unsigned u; } x;
  x.f = v;              a = (u16)(x.u >> 16);
  float r1 = v - bfu2f(a);
  x.f = r1;             b = (u16)(x.u >> 16);
  float r2 = r1 - bfu2f(b);
  x.f = r2;             c = (u16)(x.u >> 16);   // r2 exactly representable
}

__device__ __forceinline__ void mfma_bf(f32x4& acc, u16x8 a, u16x8 b) {
  asm volatile("v_mfma_f32_16x16x32_bf16 %0, %1, %2, %0" : "+v"(acc) : "v"(a), "v"(b));
}
__device__ __forceinline__ void mfma_h(f32x4& acc, u16x8 a, u16x8 b) {
  asm volatile("v_mfma_f32_16x16x32_f16 %0, %1, %2, %0" : "+v"(acc) : "v"(a), "v"(b));
}
__device__ __forceinline__ void gload16(const void* g, void* l) {
  __builtin_amdgcn_global_load_lds(
      (const __attribute__((address_space(1))) unsigned int*)g,
      (__attribute__((address_space(3))) unsigned int*)l, 16, 0, 0);
}

// ---------------- weight / input prep ----------------

__global__ void k_split_x(const float* __restrict__ in, u16* __restrict__ xh, u16* __restrict__ xl) {
  int k = blockIdx.x * 64 + threadIdx.x;   // [0,704)
  int r = blockIdx.y;                      // r = t*256 + b
  int t = r >> 8, b = r & 255;
  float v = (k < NIN_) ? in[(b * WIN_ + t) * NIN_ + k] : 0.f;
  u16 h = f2h(v);
  u16 lo = f2h(v - h2f(h));
  xh[r * NINP_ + k] = h;
  xl[r * NINP_ + k] = lo;
}

__global__ void k_split_w0(const float* __restrict__ w, u16* __restrict__ wh, u16* __restrict__ wl) {
  int k = blockIdx.x * 64 + threadIdx.x;   // [0,704)
  int j = blockIdx.y;                      // [0,512)
  float v = (k < NIN_) ? w[j * NIN_ + k] * 256.0f : 0.f;  // scale keeps low limb normal
  u16 h = f2h(v);
  u16 lo = f2h(v - h2f(h));
  wh[j * NINP_ + k] = h;
  wl[j * NINP_ + k] = lo;
}

// permute K: k' = d*512 + h  <-  reference col h*10 + d; exact 3-way bf16 split
__global__ void k_permsplit_w1(const float* __restrict__ w, u16* __restrict__ wh,
                               u16* __restrict__ wm, u16* __restrict__ wl) {
  int k = blockIdx.x * 64 + threadIdx.x;   // [0,5120)
  int j = blockIdx.y;                      // [0,512)
  int d = k >> 9, h = k & 511;
  u16 a, b, c;
  split3_bf(w[j * KBIG_ + h * ND_ + d], a, b, c);
  wh[j * KBIG_ + k] = a;
  wm[j * KBIG_ + k] = b;
  wl[j * KBIG_ + k] = c;
}

__global__ void k_permsplit_wo(const float* __restrict__ w, u16* __restrict__ wh,
                               u16* __restrict__ wm, u16* __restrict__ wl) {
  int k = blockIdx.x * 64 + threadIdx.x;   // [0,5120)
  int j = blockIdx.y;                      // [0,32)
  int d = k >> 9, h = k & 511;
  u16 a, b, c;
  float v = (j < NOUT_) ? w[j * KBIG_ + h * ND_ + d] : 0.f;
  split3_bf(v, a, b, c);
  wh[j * KBIG_ + k] = a;
  wm[j * KBIG_ + k] = b;
  wl[j * KBIG_ + k] = c;
}

// ---------------- GEMM 0: cur1 = X @ W0^T  (fp16 2x2 split, 4 exact-ish terms) ----------------

__global__ __launch_bounds__(256) void k_gemm0(const u16* __restrict__ Xh, const u16* __restrict__ Xl,
                                               const u16* __restrict__ Wh, const u16* __restrict__ Wl,
                                               float* __restrict__ out) {
  __shared__ alignas(16) u16 lAh[128 * 32], lAl[128 * 32], lBh[128 * 32], lBl[128 * 32];
  const int tid = threadIdx.x, lane = tid & 63, wid = tid >> 6;
  const int m0 = blockIdx.y * 128, n0 = blockIdx.x * 128;
  const int wr = wid >> 1, wc = wid & 1;
  const int srow = lane >> 2;
  const int sk = 8 * ((lane & 3) ^ ((lane >> 3) & 3));  // source-side XOR swizzle (16B units)
  const int fr = lane & 15, kb = lane >> 4;
  int aoff[4], boff[4];
#pragma unroll
  for (int f = 0; f < 4; f++) {
    int row = wr * 64 + f * 16 + fr;
    aoff[f] = row * 32 + (kb ^ ((row >> 1) & 3)) * 8;
    int col = wc * 64 + f * 16 + fr;
    boff[f] = col * 32 + (kb ^ ((col >> 1) & 3)) * 8;
  }
  f32x4 acc[4][4] = {};
#pragma unroll 1
  for (int kk = 0; kk < NINP_ / 32; kk++) {
    const int k0 = kk * 32;
#pragma unroll
    for (int i = 0; i < 2; i++) {
      int c = wid + 4 * i;
      int ga = (m0 + c * 16 + srow) * NINP_ + k0 + sk;
      gload16(Xh + ga, &lAh[c * 512]);
      gload16(Xl + ga, &lAl[c * 512]);
      int gb = (n0 + c * 16 + srow) * NINP_ + k0 + sk;
      gload16(Wh + gb, &lBh[c * 512]);
      gload16(Wl + gb, &lBl[c * 512]);
    }
    asm volatile("s_waitcnt vmcnt(0)" ::: "memory");
    __syncthreads();
    u16x8 bh[4], bl[4];
#pragma unroll
    for (int j = 0; j < 4; j++) {
      bh[j] = *(const u16x8*)&lBh[boff[j]];
      bl[j] = *(const u16x8*)&lBl[boff[j]];
    }
#pragma unroll
    for (int i = 0; i < 4; i++) {
      u16x8 ah = *(const u16x8*)&lAh[aoff[i]];
      u16x8 al = *(const u16x8*)&lAl[aoff[i]];
#pragma unroll
      for (int j = 0; j < 4; j++) {
        mfma_h(acc[i][j], ah, bh[j]);
        mfma_h(acc[i][j], ah, bl[j]);
        mfma_h(acc[i][j], al, bh[j]);
        mfma_h(acc[i][j], al, bl[j]);
      }
    }
    __syncthreads();
  }
  asm volatile("s_nop 7\n\ts_nop 7" ::: "memory");
#pragma unroll
  for (int i = 0; i < 4; i++) {
    int row = m0 + wr * 64 + i * 16 + (lane >> 4) * 4;
#pragma unroll
    for (int j = 0; j < 4; j++) {
      int col = n0 + wc * 64 + j * 16 + fr;
#pragma unroll
      for (int r = 0; r < 4; r++)
        out[(row + r) * H_ + col] = acc[i][j][r] * (1.0f / 256.0f);  // undo W0 scale (exact)
    }
  }
}

// ---------------- GEMM spk: cur2 = gather(S1) @ W1p^T  (binary A, exact 3-term B) ----------------

__global__ __launch_bounds__(256) void k_gemm_spk(const u16* __restrict__ S, const u16* __restrict__ Wh,
                                                  const u16* __restrict__ Wm, const u16* __restrict__ Wl,
                                                  float* __restrict__ out) {
  __shared__ alignas(16) u16 lA[128 * 32], lBh[128 * 32], lBm[128 * 32], lBl[128 * 32];
  const int tid = threadIdx.x, lane = tid & 63, wid = tid >> 6;
  const int mt = blockIdx.y;
  const int m0 = mt * 128, n0 = blockIdx.x * 128;
  const int t = mt >> 1, brow0 = (mt & 1) * 128;
  const int wr = wid >> 1, wc = wid & 1;
  const int srow = lane >> 2;
  const int sk = 8 * ((lane & 3) ^ ((lane >> 3) & 3));
  const int fr = lane & 15, kb = lane >> 4;
  int aoff[4], boff[4];
#pragma unroll
  for (int f = 0; f < 4; f++) {
    int row = wr * 64 + f * 16 + fr;
    aoff[f] = row * 32 + (kb ^ ((row >> 1) & 3)) * 8;
    int col = wc * 64 + f * 16 + fr;
    boff[f] = col * 32 + (kb ^ ((col >> 1) & 3)) * 8;
  }
  f32x4 acc[4][4] = {};
#pragma unroll 1
  for (int kk = 0; kk < KBIG_ / 32; kk++) {
    const int k0 = kk * 32;
    const int d = k0 >> 9, h0 = k0 & 511;
    const int p = t + 4 * d;  // S plane; planes [0,40) are zero history
#pragma unroll
    for (int i = 0; i < 2; i++) {
      int c = wid + 4 * i;
      gload16(S + ((p * 256 + brow0 + c * 16 + srow) * 512 + h0 + sk), &lA[c * 512]);
      int gb = (n0 + c * 16 + srow) * KBIG_ + k0 + sk;
      gload16(Wh + gb, &lBh[c * 512]);
      gload16(Wm + gb, &lBm[c * 512]);
      gload16(Wl + gb, &lBl[c * 512]);
    }
    asm volatile("s_waitcnt vmcnt(0)" ::: "memory");
    __syncthreads();
    u16x8 bh[4], bm[4], bl[4];
#pragma unroll
    for (int j = 0; j < 4; j++) {
      bh[j] = *(const u16x8*)&lBh[boff[j]];
      bm[j] = *(const u16x8*)&lBm[boff[j]];
      bl[j] = *(const u16x8*)&lBl[boff[j]];
    }
#pragma unroll
    for (int i = 0; i < 4; i++) {
      u16x8 a = *(const u16x8*)&lA[aoff[i]];
#pragma unroll
      for (int j = 0; j < 4; j++) {
        mfma_bf(acc[i][j], a, bh[j]);
        mfma_bf(acc[i][j], a, bm[j]);
        mfma_bf(acc[i][j], a, bl[j]);
      }
    }
    __syncthreads();
  }
  asm volatile("s_nop 7\n\ts_nop 7" ::: "memory");
#pragma unroll
  for (int i = 0; i < 4; i++) {
    int row = m0 + wr * 64 + i * 16 + (lane >> 4) * 4;
#pragma unroll
    for (int j = 0; j < 4; j++) {
      int col = n0 + wc * 64 + j * 16 + fr;
#pragma unroll
      for (int r = 0; r < 4; r++) out[(row + r) * H_ + col] = acc[i][j][r];
    }
  }
}

// ---------------- GEMM out: curo = gather(S2) @ Wop^T  (N=32 padded, exact 3-term B) ----------------

__global__ __launch_bounds__(256) void k_gemm_out(const u16* __restrict__ S, const u16* __restrict__ Wh,
                                                  const u16* __restrict__ Wm, const u16* __restrict__ Wl,
                                                  float* __restrict__ out) {
  __shared__ alignas(16) u16 lA[128 * 32], lBh[32 * 32], lBm[32 * 32], lBl[32 * 32];
  const int tid = threadIdx.x, lane = tid & 63, wid = tid >> 6;
  const int mt = blockIdx.x;
  const int m0 = mt * 128;
  const int t = mt >> 1, brow0 = (mt & 1) * 128;
  const int srow = lane >> 2;
  const int sk = 8 * ((lane & 3) ^ ((lane >> 3) & 3));
  const int fr = lane & 15, kb = lane >> 4;
  int aoff[2], boff[2];
#pragma unroll
  for (int f = 0; f < 2; f++) {
    int row = wid * 32 + f * 16 + fr;
    aoff[f] = row * 32 + (kb ^ ((row >> 1) & 3)) * 8;
    int col = f * 16 + fr;
    boff[f] = col * 32 + (kb ^ ((col >> 1) & 3)) * 8;
  }
  f32x4 acc[2][2] = {};
#pragma unroll 1
  for (int kk = 0; kk < KBIG_ / 32; kk++) {
    const int k0 = kk * 32;
    const int d = k0 >> 9, h0 = k0 & 511;
    const int p = t + 4 * d;
#pragma unroll
    for (int i = 0; i < 2; i++) {
      int c = wid + 4 * i;
      gload16(S + ((p * 256 + brow0 + c * 16 + srow) * 512 + h0 + sk), &lA[c * 512]);
    }
    {  // 6 B chunks (3 buffers x 2 halves) over 4 waves
      const u16* bs = (wid < 2) ? Wh : Wm;
      u16* bd = (wid < 2) ? (u16*)lBh : (u16*)lBm;
      int half = wid & 1;
      gload16(bs + (half * 16 + srow) * KBIG_ + k0 + sk, &bd[half * 512]);
      if (wid < 2) gload16(Wl + (wid * 16 + srow) * KBIG_ + k0 + sk, &lBl[wid * 512]);
    }
    asm volatile("s_waitcnt vmcnt(0)" ::: "memory");
    __syncthreads();
    u16x8 bh[2], bm[2], bl[2];
#pragma unroll
    for (int j = 0; j < 2; j++) {
      bh[j] = *(const u16x8*)&lBh[boff[j]];
      bm[j] = *(const u16x8*)&lBm[boff[j]];
      bl[j] = *(const u16x8*)&lBl[boff[j]];
    }
#pragma unroll
    for (int i = 0; i < 2; i++) {
      u16x8 a = *(const u16x8*)&lA[aoff[i]];
#pragma unroll
      for (int j = 0; j < 2; j++) {
        mfma_bf(acc[i][j], a, bh[j]);
        mfma_bf(acc[i][j], a, bm[j]);
        mfma_bf(acc[i][j], a, bl[j]);
      }
    }
    __syncthreads();
  }
  asm volatile("s_nop 7\n\ts_nop 7" ::: "memory");
#pragma unroll
  for (int i = 0; i < 2; i++) {
    int row = m0 + wid * 32 + i * 16 + (lane >> 4) * 4;
#pragma unroll
    for (int j = 0; j < 2; j++) {
      int col = j * 16 + fr;
#pragma unroll
      for (int r = 0; r < 4; r++) out[(row + r) * NOUTP_ + col] = acc[i][j][r];
    }
  }
}

// ---------------- elementwise LIF scans (strict fp32 rounding, no contraction) ----------------

__global__ void k_scan(const float* __restrict__ cur, const float* __restrict__ tau, u16* __restrict__ S) {
  int g = blockIdx.x * 256 + threadIdx.x;   // [0, 131072)
  int b = g >> 9, h = g & 511;
  float a = (float)(1.0 / (1.0 + exp(-(double)tau[h])));
  float mem = 0.f, s = 0.f;
#pragma unroll 1
  for (int t = 0; t < WIN_; t++) {
    float c = cur[(t * 256 + b) * 512 + h];
    mem = __fadd_rn(__fmul_rn(__fmul_rn(mem, a), __fsub_rn(1.f, s)), c);
    float x = __fsub_rn(mem, THRESH_);
    s = (x > 0.f) ? 1.f : 0.f;
    mem = (mem < THRESH_) ? mem : 0.f;
    S[((t + 40) * 256 + b) * 512 + h] = (x > 0.f) ? (u16)0x3F80 : (u16)0;
  }
}

__global__ void k_scan_o(const float* __restrict__ curo, const float* __restrict__ tau, float* __restrict__ outp) {
  int b = blockIdx.x * 64 + threadIdx.x;
  if (b >= B_) return;
  float ao[NOUT_], mem[NOUT_], spk[NOUT_], osum[NOUT_], mot[NOUT_];
#pragma unroll
  for (int j = 0; j < NOUT_; j++) {
    ao[j] = (float)(1.0 / (1.0 + exp(-(double)tau[j])));
    mem[j] = 0.f; spk[j] = 0.f; osum[j] = 0.f; mot[j] = 0.f;
  }
#pragma unroll 1
  for (int t = 0; t < WIN_; t++) {
    const float4* rowp = (const float4*)&curo[(t * 256 + b) * NOUTP_];
    float4 v[5];
#pragma unroll
    for (int q = 0; q < 5; q++) v[q] = rowp[q];
    float cv[NOUT_];
#pragma unroll
    for (int q = 0; q < 5; q++) {
      cv[4 * q + 0] = v[q].x; cv[4 * q + 1] = v[q].y;
      cv[4 * q + 2] = v[q].z; cv[4 * q + 3] = v[q].w;
    }
    float mx = -1e30f;
#pragma unroll
    for (int j = 0; j < NOUT_; j++) {
      mem[j] = __fadd_rn(__fmul_rn(__fmul_rn(mem[j], ao[j]), __fsub_rn(1.f, spk[j])), cv[j]);
      float x = __fsub_rn(mem[j], THRESH_);
      spk[j] = (x > 0.f) ? 1.f : 0.f;
      mem[j] = (mem[j] < THRESH_) ? mem[j] : 0.f;
      osum[j] = __fadd_rn(osum[j], spk[j]);
      mx = fmaxf(mx, mem[j]);
    }
    float se = 0.f, e[NOUT_];
#pragma unroll
    for (int j = 0; j < NOUT_; j++) { e[j] = expf(__fsub_rn(mem[j], mx)); se = __fadd_rn(se, e[j]); }
#pragma unroll
    for (int j = 0; j < NOUT_; j++) mot[j] = __fadd_rn(mot[j], __fdiv_rn(e[j], se));
  }
#pragma unroll
  for (int j = 0; j < NOUT_; j++) {
    outp[b * NOUT_ + j] = __fdiv_rn(osum[j], 100.0f);
    outp[B_ * NOUT_ + b * NOUT_ + j] = mot[j];
  }
}

// ---------------- launch ----------------

extern "C" void kernel_launch(void* const* d_in, const int* in_sizes, int n_in,
                              void* d_out, int out_size, void* d_ws, size_t ws_size,
                              hipStream_t stream) {
  const float* in   = (const float*)d_in[0];
  const float* W0   = (const float*)d_in[1];
  const float* W1   = (const float*)d_in[2];
  const float* Wo   = (const float*)d_in[3];
  const float* tau1 = (const float*)d_in[4];
  const float* tau2 = (const float*)d_in[5];
  const float* tauo = (const float*)d_in[6];
  float* out = (float*)d_out;

  char* ws = (char*)d_ws;
  size_t off = 0;
  auto take = [&](size_t bytes) -> char* {
    char* p = ws + off;
    off += (bytes + 255) & ~(size_t)255;
    return p;
  };
  u16* Xh  = (u16*)take((size_t)M_ * NINP_ * 2);
  u16* Xl  = (u16*)take((size_t)M_ * NINP_ * 2);
  u16* W0h = (u16*)take((size_t)H_ * NINP_ * 2);
  u16* W0l = (u16*)take((size_t)H_ * NINP_ * 2);
  u16* W1h = (u16*)take((size_t)H_ * KBIG_ * 2);
  u16* W1m = (u16*)take((size_t)H_ * KBIG_ * 2);
  u16* W1l = (u16*)take((size_t)H_ * KBIG_ * 2);
  u16* Woh = (u16*)take((size_t)NOUTP_ * KBIG_ * 2);
  u16* Wom = (u16*)take((size_t)NOUTP_ * KBIG_ * 2);
  u16* Wol = (u16*)take((size_t)NOUTP_ * KBIG_ * 2);
  float* cur1 = (float*)take((size_t)M_ * H_ * 4);
  float* cur2 = (float*)take((size_t)M_ * H_ * 4);
  float* curo = (float*)take((size_t)M_ * NOUTP_ * 4);
  u16* S1 = (u16*)take((size_t)PLANES_ * B_ * H_ * 2);
  u16* S2 = (u16*)take((size_t)PLANES_ * B_ * H_ * 2);

  hipMemsetAsync(S1, 0, (size_t)40 * B_ * H_ * 2, stream);
  hipMemsetAsync(S2, 0, (size_t)40 * B_ * H_ * 2, stream);

  k_split_x<<<dim3(11, M_), 64, 0, stream>>>(in, Xh, Xl);
  k_split_w0<<<dim3(11, H_), 64, 0, stream>>>(W0, W0h, W0l);
  k_permsplit_w1<<<dim3(80, H_), 64, 0, stream>>>(W1, W1h, W1m, W1l);
  k_permsplit_wo<<<dim3(80, NOUTP_), 64, 0, stream>>>(Wo, Woh, Wom, Wol);

  k_gemm0<<<dim3(4, 200), 256, 0, stream>>>(Xh, Xl, W0h, W0l, cur1);
  k_scan<<<dim3(512), 256, 0, stream>>>(cur1, tau1, S1);
  k_gemm_spk<<<dim3(4, 200), 256, 0, stream>>>(S1, W1h, W1m, W1l, cur2);
  k_scan<<<dim3(512), 256, 0, stream>>>(cur2, tau2, S2);
  k_gemm_out<<<dim3(200), 256, 0, stream>>>(S2, Woh, Wom, Wol, curo);
  k_scan_o<<<dim3(4), 64, 0, stream>>>(curo, tauo, out);
}

// Round 3
// 781.454 us; speedup vs baseline: 1.1871x; 1.1871x over previous
//
#include <hip/hip_runtime.h>
#include <stdint.h>

#define THRESH_ 0.3f
constexpr int B_ = 256, WIN_ = 100, NIN_ = 700, NINP_ = 704, H_ = 512;
constexpr int NOUT_ = 20, NOUTP_ = 32, ND_ = 10, KBIG_ = 5120, M_ = 25600;
constexpr int PLANES_ = 140;  // 40 zero-history + 100

typedef unsigned short u16;
typedef unsigned short u16x8 __attribute__((ext_vector_type(8)));
typedef float f32x4 __attribute__((ext_vector_type(4)));

// ---- fp16 RNE split ----
__device__ __forceinline__ u16 f2h(float f) {
  _Float16 h = (_Float16)f;           // RNE
  union { _Float16 h; u16 u; } v; v.h = h;
  return v.u;
}
__device__ __forceinline__ float h2f(u16 u) {
  union { u16 u; _Float16 h; } v; v.u = u;
  return (float)v.h;
}

__device__ __forceinline__ void mfma_h(f32x4& acc, u16x8 a, u16x8 b) {
  asm volatile("v_mfma_f32_16x16x32_f16 %0, %1, %2, %0" : "+v"(acc) : "v"(a), "v"(b));
}
__device__ __forceinline__ void gload16(const void* g, void* l) {
  __builtin_amdgcn_global_load_lds(
      (const __attribute__((address_space(1))) unsigned int*)g,
      (__attribute__((address_space(3))) unsigned int*)l, 16, 0, 0);
}

// ---------------- weight / input prep ----------------

__global__ void k_split_x(const float* __restrict__ in, u16* __restrict__ xh, u16* __restrict__ xl) {
  int k = blockIdx.x * 64 + threadIdx.x;   // [0,704)
  int r = blockIdx.y;                      // r = t*256 + b
  int t = r >> 8, b = r & 255;
  float v = (k < NIN_) ? in[(b * WIN_ + t) * NIN_ + k] : 0.f;
  u16 h = f2h(v);
  u16 lo = f2h(v - h2f(h));
  xh[r * NINP_ + k] = h;
  xl[r * NINP_ + k] = lo;
}

__global__ void k_split_w0(const float* __restrict__ w, u16* __restrict__ wh, u16* __restrict__ wl) {
  int k = blockIdx.x * 64 + threadIdx.x;   // [0,704)
  int j = blockIdx.y;                      // [0,512)
  float v = (k < NIN_) ? w[j * NIN_ + k] * 256.0f : 0.f;  // scale keeps low limb normal
  u16 h = f2h(v);
  u16 lo = f2h(v - h2f(h));
  wh[j * NINP_ + k] = h;
  wl[j * NINP_ + k] = lo;
}

// permute K: k' = d*512 + h  <-  reference col h*10 + d; 2-limb fp16, scaled x256
__global__ void k_permsplit_w1(const float* __restrict__ w, u16* __restrict__ wh, u16* __restrict__ wl) {
  int k = blockIdx.x * 64 + threadIdx.x;   // [0,5120)
  int j = blockIdx.y;                      // [0,512)
  int d = k >> 9, h = k & 511;
  float v = w[j * KBIG_ + h * ND_ + d] * 256.0f;
  u16 a = f2h(v);
  u16 b = f2h(v - h2f(a));
  wh[j * KBIG_ + k] = a;
  wl[j * KBIG_ + k] = b;
}

__global__ void k_permsplit_wo(const float* __restrict__ w, u16* __restrict__ wh, u16* __restrict__ wl) {
  int k = blockIdx.x * 64 + threadIdx.x;   // [0,5120)
  int j = blockIdx.y;                      // [0,32)
  int d = k >> 9, h = k & 511;
  float v = (j < NOUT_) ? w[j * KBIG_ + h * ND_ + d] * 256.0f : 0.f;
  u16 a = f2h(v);
  u16 b = f2h(v - h2f(a));
  wh[j * KBIG_ + k] = a;
  wl[j * KBIG_ + k] = b;
}

// ---------------- GEMM 0: cur1 = X @ W0^T  (fp16 2x2 split, 4 terms, BK=32) ----------------

__global__ __launch_bounds__(256) void k_gemm0(const u16* __restrict__ Xh, const u16* __restrict__ Xl,
                                               const u16* __restrict__ Wh, const u16* __restrict__ Wl,
                                               float* __restrict__ out) {
  __shared__ alignas(16) u16 lAh[128 * 32], lAl[128 * 32], lBh[128 * 32], lBl[128 * 32];
  const int tid = threadIdx.x, lane = tid & 63, wid = tid >> 6;
  const int m0 = blockIdx.y * 128, n0 = blockIdx.x * 128;
  const int wr = wid >> 1, wc = wid & 1;
  const int srow = lane >> 2;
  const int sk = 8 * ((lane & 3) ^ ((lane >> 3) & 3));  // source-side XOR swizzle (16B units)
  const int fr = lane & 15, kb = lane >> 4;
  int aoff[4], boff[4];
#pragma unroll
  for (int f = 0; f < 4; f++) {
    int row = wr * 64 + f * 16 + fr;
    aoff[f] = row * 32 + (kb ^ ((row >> 1) & 3)) * 8;
    int col = wc * 64 + f * 16 + fr;
    boff[f] = col * 32 + (kb ^ ((col >> 1) & 3)) * 8;
  }
  f32x4 acc[4][4] = {};
#pragma unroll 1
  for (int kk = 0; kk < NINP_ / 32; kk++) {
    const int k0 = kk * 32;
#pragma unroll
    for (int i = 0; i < 2; i++) {
      int c = wid + 4 * i;
      int ga = (m0 + c * 16 + srow) * NINP_ + k0 + sk;
      gload16(Xh + ga, &lAh[c * 512]);
      gload16(Xl + ga, &lAl[c * 512]);
      int gb = (n0 + c * 16 + srow) * NINP_ + k0 + sk;
      gload16(Wh + gb, &lBh[c * 512]);
      gload16(Wl + gb, &lBl[c * 512]);
    }
    asm volatile("s_waitcnt vmcnt(0)" ::: "memory");
    __syncthreads();
    u16x8 bh[4], bl[4];
#pragma unroll
    for (int j = 0; j < 4; j++) {
      bh[j] = *(const u16x8*)&lBh[boff[j]];
      bl[j] = *(const u16x8*)&lBl[boff[j]];
    }
#pragma unroll
    for (int i = 0; i < 4; i++) {
      u16x8 ah = *(const u16x8*)&lAh[aoff[i]];
      u16x8 al = *(const u16x8*)&lAl[aoff[i]];
#pragma unroll
      for (int j = 0; j < 4; j++) {
        mfma_h(acc[i][j], ah, bh[j]);
        mfma_h(acc[i][j], ah, bl[j]);
        mfma_h(acc[i][j], al, bh[j]);
        mfma_h(acc[i][j], al, bl[j]);
      }
    }
    __syncthreads();
  }
  asm volatile("s_nop 7\n\ts_nop 7" ::: "memory");
#pragma unroll
  for (int i = 0; i < 4; i++) {
    int row = m0 + wr * 64 + i * 16 + (lane >> 4) * 4;
#pragma unroll
    for (int j = 0; j < 4; j++) {
      int col = n0 + wc * 64 + j * 16 + fr;
#pragma unroll
      for (int r = 0; r < 4; r++)
        out[(row + r) * H_ + col] = acc[i][j][r] * (1.0f / 256.0f);  // undo W0 scale (exact)
    }
  }
}

// ---------------- GEMM spk: cur2 = gather(S1) @ W1p^T  (fp16 spikes, 2-limb B, BK=64) ----------------

__global__ __launch_bounds__(256) void k_gemm_spk(const u16* __restrict__ S, const u16* __restrict__ Wh,
                                                  const u16* __restrict__ Wl, float* __restrict__ out) {
  __shared__ alignas(16) u16 lA[128 * 64], lBh[128 * 64], lBl[128 * 64];  // 48 KB
  const int tid = threadIdx.x, lane = tid & 63, wid = tid >> 6;
  const int mt = blockIdx.y;
  const int m0 = mt * 128, n0 = blockIdx.x * 128;
  const int t = mt >> 1, brow0 = (mt & 1) * 128;
  const int wr = wid >> 1, wc = wid & 1;
  // staging: each gload stages 8 rows x 128B; lane -> (row = lane>>3, slot = lane&7)
  const int srow8 = lane >> 3;
  const int ksrc = ((lane >> 2) & 1) * 32 + 8 * ((lane & 3) ^ ((lane >> 4) & 3));
  const int fr = lane & 15, kb = lane >> 4;
  const int kx = (kb ^ ((fr >> 1) & 3)) * 8;  // swizzled 16B slot within 32-K half
  int aoff[4], boff[4];
#pragma unroll
  for (int f = 0; f < 4; f++) {
    aoff[f] = (wr * 64 + f * 16 + fr) * 64 + kx;
    boff[f] = (wc * 64 + f * 16 + fr) * 64 + kx;
  }
  f32x4 acc[4][4] = {};
#pragma unroll 1
  for (int kk = 0; kk < KBIG_ / 64; kk++) {
    const int k0 = kk * 64;
    const int d = k0 >> 9, h0 = k0 & 511;
    const int p = t + 4 * d;  // S plane; planes [0,40) are zero history
    const u16* Sb = S + (size_t)(p * 256 + brow0) * 512 + h0 + ksrc;
#pragma unroll
    for (int c = 0; c < 4; c++) {
      int rb = c * 32 + wid * 8;
      gload16(Sb + (rb + srow8) * 512, &lA[rb * 64]);
      size_t gb = (size_t)(n0 + rb + srow8) * KBIG_ + k0 + ksrc;
      gload16(Wh + gb, &lBh[rb * 64]);
      gload16(Wl + gb, &lBl[rb * 64]);
    }
    asm volatile("s_waitcnt vmcnt(0)" ::: "memory");
    __syncthreads();
#pragma unroll
    for (int s = 0; s < 2; s++) {
      const int so = s * 32;
      u16x8 bh[4], bl[4];
#pragma unroll
      for (int j = 0; j < 4; j++) {
        bh[j] = *(const u16x8*)&lBh[boff[j] + so];
        bl[j] = *(const u16x8*)&lBl[boff[j] + so];
      }
#pragma unroll
      for (int i = 0; i < 4; i++) {
        u16x8 a = *(const u16x8*)&lA[aoff[i] + so];
#pragma unroll
        for (int j = 0; j < 4; j++) {
          mfma_h(acc[i][j], a, bh[j]);
          mfma_h(acc[i][j], a, bl[j]);
        }
      }
    }
    __syncthreads();
  }
  asm volatile("s_nop 7\n\ts_nop 7" ::: "memory");
#pragma unroll
  for (int i = 0; i < 4; i++) {
    int row = m0 + wr * 64 + i * 16 + (lane >> 4) * 4;
#pragma unroll
    for (int j = 0; j < 4; j++) {
      int col = n0 + wc * 64 + j * 16 + fr;
#pragma unroll
      for (int r = 0; r < 4; r++)
        out[(row + r) * H_ + col] = acc[i][j][r] * (1.0f / 256.0f);  // undo W1 scale
    }
  }
}

// ---------------- GEMM out: curo = gather(S2) @ Wop^T  (N=32 padded, 2-limb, BK=32) ----------------

__global__ __launch_bounds__(256) void k_gemm_out(const u16* __restrict__ S, const u16* __restrict__ Wh,
                                                  const u16* __restrict__ Wl, float* __restrict__ out) {
  __shared__ alignas(16) u16 lA[128 * 32], lBh[32 * 32], lBl[32 * 32];
  const int tid = threadIdx.x, lane = tid & 63, wid = tid >> 6;
  const int mt = blockIdx.x;
  const int m0 = mt * 128;
  const int t = mt >> 1, brow0 = (mt & 1) * 128;
  const int srow = lane >> 2;
  const int sk = 8 * ((lane & 3) ^ ((lane >> 3) & 3));
  const int fr = lane & 15, kb = lane >> 4;
  int aoff[2], boff[2];
#pragma unroll
  for (int f = 0; f < 2; f++) {
    int row = wid * 32 + f * 16 + fr;
    aoff[f] = row * 32 + (kb ^ ((row >> 1) & 3)) * 8;
    int col = f * 16 + fr;
    boff[f] = col * 32 + (kb ^ ((col >> 1) & 3)) * 8;
  }
  f32x4 acc[2][2] = {};
#pragma unroll 1
  for (int kk = 0; kk < KBIG_ / 32; kk++) {
    const int k0 = kk * 32;
    const int d = k0 >> 9, h0 = k0 & 511;
    const int p = t + 4 * d;
#pragma unroll
    for (int i = 0; i < 2; i++) {
      int c = wid + 4 * i;
      gload16(S + ((size_t)(p * 256 + brow0 + c * 16 + srow) * 512 + h0 + sk), &lA[c * 512]);
    }
    {  // 4 B chunks (2 buffers x 2 halves) over 4 waves
      const u16* bs = (wid < 2) ? Wh : Wl;
      u16* bd = (wid < 2) ? (u16*)lBh : (u16*)lBl;
      int half = wid & 1;
      gload16(bs + (size_t)(half * 16 + srow) * KBIG_ + k0 + sk, &bd[half * 512]);
    }
    asm volatile("s_waitcnt vmcnt(0)" ::: "memory");
    __syncthreads();
    u16x8 bh[2], bl[2];
#pragma unroll
    for (int j = 0; j < 2; j++) {
      bh[j] = *(const u16x8*)&lBh[boff[j]];
      bl[j] = *(const u16x8*)&lBl[boff[j]];
    }
#pragma unroll
    for (int i = 0; i < 2; i++) {
      u16x8 a = *(const u16x8*)&lA[aoff[i]];
#pragma unroll
      for (int j = 0; j < 2; j++) {
        mfma_h(acc[i][j], a, bh[j]);
        mfma_h(acc[i][j], a, bl[j]);
      }
    }
    __syncthreads();
  }
  asm volatile("s_nop 7\n\ts_nop 7" ::: "memory");
#pragma unroll
  for (int i = 0; i < 2; i++) {
    int row = m0 + wid * 32 + i * 16 + (lane >> 4) * 4;
#pragma unroll
    for (int j = 0; j < 2; j++) {
      int col = j * 16 + fr;
#pragma unroll
      for (int r = 0; r < 4; r++)
        out[(row + r) * NOUTP_ + col] = acc[i][j][r] * (1.0f / 256.0f);  // undo Wo scale
    }
  }
}

// ---------------- elementwise LIF scans (strict fp32 rounding, no contraction) ----------------

__global__ void k_scan(const float* __restrict__ cur, const float* __restrict__ tau, u16* __restrict__ S) {
  int g = blockIdx.x * 256 + threadIdx.x;   // [0, 131072)
  int b = g >> 9, h = g & 511;
  float a = (float)(1.0 / (1.0 + exp(-(double)tau[h])));
  float mem = 0.f, s = 0.f;
#pragma unroll 1
  for (int t = 0; t < WIN_; t++) {
    float c = cur[(t * 256 + b) * 512 + h];
    mem = __fadd_rn(__fmul_rn(__fmul_rn(mem, a), __fsub_rn(1.f, s)), c);
    float x = __fsub_rn(mem, THRESH_);
    s = (x > 0.f) ? 1.f : 0.f;
    mem = (mem < THRESH_) ? mem : 0.f;
    S[((t + 40) * 256 + b) * 512 + h] = (x > 0.f) ? (u16)0x3C00 : (u16)0;  // fp16 1.0
  }
}

__global__ void k_scan_o(const float* __restrict__ curo, const float* __restrict__ tau, float* __restrict__ outp) {
  int b = blockIdx.x * 64 + threadIdx.x;
  if (b >= B_) return;
  float ao[NOUT_], mem[NOUT_], spk[NOUT_], osum[NOUT_], mot[NOUT_];
#pragma unroll
  for (int j = 0; j < NOUT_; j++) {
    ao[j] = (float)(1.0 / (1.0 + exp(-(double)tau[j])));
    mem[j] = 0.f; spk[j] = 0.f; osum[j] = 0.f; mot[j] = 0.f;
  }
#pragma unroll 1
  for (int t = 0; t < WIN_; t++) {
    const float4* rowp = (const float4*)&curo[(t * 256 + b) * NOUTP_];
    float4 v[5];
#pragma unroll
    for (int q = 0; q < 5; q++) v[q] = rowp[q];
    float cv[NOUT_];
#pragma unroll
    for (int q = 0; q < 5; q++) {
      cv[4 * q + 0] = v[q].x; cv[4 * q + 1] = v[q].y;
      cv[4 * q + 2] = v[q].z; cv[4 * q + 3] = v[q].w;
    }
#pragma unroll
    for (int j = 0; j < NOUT_; j++) {
      mem[j] = __fadd_rn(__fmul_rn(__fmul_rn(mem[j], ao[j]), __fsub_rn(1.f, spk[j])), cv[j]);
      float x = __fsub_rn(mem[j], THRESH_);
      spk[j] = (x > 0.f) ? 1.f : 0.f;
      mem[j] = (mem[j] < THRESH_) ? mem[j] : 0.f;
      osum[j] = __fadd_rn(osum[j], spk[j]);
    }
    float mx = -1e30f;
#pragma unroll
    for (int j = 0; j < NOUT_; j++) mx = fmaxf(mx, mem[j]);
    float se = 0.f, e[NOUT_];
#pragma unroll
    for (int j = 0; j < NOUT_; j++) { e[j] = expf(__fsub_rn(mem[j], mx)); se = __fadd_rn(se, e[j]); }
#pragma unroll
    for (int j = 0; j < NOUT_; j++) mot[j] = __fadd_rn(mot[j], __fdiv_rn(e[j], se));
  }
#pragma unroll
  for (int j = 0; j < NOUT_; j++) {
    outp[b * NOUT_ + j] = __fdiv_rn(osum[j], 100.0f);
    outp[B_ * NOUT_ + b * NOUT_ + j] = mot[j];
  }
}

// ---------------- launch ----------------

extern "C" void kernel_launch(void* const* d_in, const int* in_sizes, int n_in,
                              void* d_out, int out_size, void* d_ws, size_t ws_size,
                              hipStream_t stream) {
  const float* in   = (const float*)d_in[0];
  const float* W0   = (const float*)d_in[1];
  const float* W1   = (const float*)d_in[2];
  const float* Wo   = (const float*)d_in[3];
  const float* tau1 = (const float*)d_in[4];
  const float* tau2 = (const float*)d_in[5];
  const float* tauo = (const float*)d_in[6];
  float* out = (float*)d_out;

  char* ws = (char*)d_ws;
  size_t off = 0;
  auto take = [&](size_t bytes) -> char* {
    char* p = ws + off;
    off += (bytes + 255) & ~(size_t)255;
    return p;
  };
  u16* Xh  = (u16*)take((size_t)M_ * NINP_ * 2);
  u16* Xl  = (u16*)take((size_t)M_ * NINP_ * 2);
  u16* W0h = (u16*)take((size_t)H_ * NINP_ * 2);
  u16* W0l = (u16*)take((size_t)H_ * NINP_ * 2);
  u16* W1h = (u16*)take((size_t)H_ * KBIG_ * 2);
  u16* W1l = (u16*)take((size_t)H_ * KBIG_ * 2);
  u16* Woh = (u16*)take((size_t)NOUTP_ * KBIG_ * 2);
  u16* Wol = (u16*)take((size_t)NOUTP_ * KBIG_ * 2);
  float* cur1 = (float*)take((size_t)M_ * H_ * 4);
  float* cur2 = (float*)take((size_t)M_ * H_ * 4);
  float* curo = (float*)take((size_t)M_ * NOUTP_ * 4);
  u16* S1 = (u16*)take((size_t)PLANES_ * B_ * H_ * 2);
  u16* S2 = (u16*)take((size_t)PLANES_ * B_ * H_ * 2);

  hipMemsetAsync(S1, 0, (size_t)40 * B_ * H_ * 2, stream);
  hipMemsetAsync(S2, 0, (size_t)40 * B_ * H_ * 2, stream);

  k_split_x<<<dim3(11, M_), 64, 0, stream>>>(in, Xh, Xl);
  k_split_w0<<<dim3(11, H_), 64, 0, stream>>>(W0, W0h, W0l);
  k_permsplit_w1<<<dim3(80, H_), 64, 0, stream>>>(W1, W1h, W1l);
  k_permsplit_wo<<<dim3(80, NOUTP_), 64, 0, stream>>>(Wo, Woh, Wol);

  k_gemm0<<<dim3(4, 200), 256, 0, stream>>>(Xh, Xl, W0h, W0l, cur1);
  k_scan<<<dim3(512), 256, 0, stream>>>(cur1, tau1, S1);
  k_gemm_spk<<<dim3(4, 200), 256, 0, stream>>>(S1, W1h, W1l, cur2);
  k_scan<<<dim3(512), 256, 0, stream>>>(cur2, tau2, S2);
  k_gemm_out<<<dim3(200), 256, 0, stream>>>(S2, Woh, Wol, curo);
  k_scan_o<<<dim3(4), 64, 0, stream>>>(curo, tauo, out);
}